// Round 1
// baseline (1575.796 us; speedup 1.0000x reference)
//
#include <hip/hip_runtime.h>

#define C_DIM 256
#define HID_DIM 512
#define NHEAD 8
#define DHEAD 32
#define WWIN 512

__device__ __forceinline__ float bf2f(unsigned int u16) {
    return __uint_as_float(u16 << 16);
}
__device__ __forceinline__ unsigned short f2bf(float f) {
    unsigned int x = __float_as_uint(f);
    return (unsigned short)((x + 0x7fffu + ((x >> 16) & 1u)) >> 16);
}
__device__ __forceinline__ void unpack8(uint4 u, float* d) {
    d[0] = bf2f(u.x & 0xffffu); d[1] = bf2f(u.x >> 16);
    d[2] = bf2f(u.y & 0xffffu); d[3] = bf2f(u.y >> 16);
    d[4] = bf2f(u.z & 0xffffu); d[5] = bf2f(u.z >> 16);
    d[6] = bf2f(u.w & 0xffffu); d[7] = bf2f(u.w >> 16);
}

// ---- per-row LayerNorm stats: one wave per row of 256 floats ----
__global__ __launch_bounds__(256) void rowstats_k(const float* __restrict__ X,
        float* __restrict__ mu, float* __restrict__ rs) {
    int lane = threadIdx.x & 63;
    int row = blockIdx.x * 4 + (threadIdx.x >> 6);
    float4 v = ((const float4*)(X + (size_t)row * C_DIM))[lane];
    float s = v.x + v.y + v.z + v.w;
    float q = v.x * v.x + v.y * v.y + v.z * v.z + v.w * v.w;
    #pragma unroll
    for (int o = 32; o; o >>= 1) { s += __shfl_xor(s, o); q += __shfl_xor(q, o); }
    if (lane == 0) {
        float m = s * (1.0f / C_DIM);
        float var = q * (1.0f / C_DIM) - m * m;
        mu[row] = m; rs[row] = rsqrtf(var + 1e-5f);
    }
}

// ---- window valid-lengths + inverse (token -> (window,offset)) map ----
__global__ __launch_bounds__(512) void wininv_k(const int* __restrict__ widx,
        int* __restrict__ wlen, int* __restrict__ cnt, int* __restrict__ inv) {
    int m = blockIdx.x, j = threadIdx.x;
    int id = widx[m * WWIN + j];
    int valid = (j == 0) || (id != widx[m * WWIN + j - 1]);
    __shared__ int part[8];
    int v = valid;
    #pragma unroll
    for (int o = 32; o; o >>= 1) v += __shfl_xor(v, o);
    if ((j & 63) == 0) part[j >> 6] = v;
    __syncthreads();
    if (j == 0) {
        int s = 0;
        #pragma unroll
        for (int i = 0; i < 8; i++) s += part[i];
        wlen[m] = s;
    }
    if (valid) {
        int slot = atomicAdd(&cnt[id], 1);
        if (slot < 2) inv[id * 2 + slot] = m * WWIN + j;
    }
}

// ---- generic tiled fp32 GEMM: out[r][c] = act(sum_k At(r,k)*B[c][k]) ----
// AMODE: 1 = fp32 A + per-row LN (rowmu/rowrs) + per-k affine (colw/colb)
//        2 = bf16 A plain
//        3 = fp32 A + relu(A*colw[k]+colb[k])   (BatchNorm+ReLU folded)
// OMODE: 0 = bf16 store (no bias); 1 = fp32 + bias; 2 = fp32 + bias + resid
template<int K, int AMODE, int OMODE>
__global__ __launch_bounds__(256, 4) void gemm_k(
        const void* __restrict__ Av, const float* __restrict__ Bw,
        const float* __restrict__ bias, void* __restrict__ Outv,
        const float* __restrict__ rowmu, const float* __restrict__ rowrs,
        const float* __restrict__ colw, const float* __restrict__ colb,
        const float* __restrict__ resid, int CN) {
    __shared__ float As[64][17];
    __shared__ float Bs[16][64];
    const int c0 = blockIdx.x * 64, r0 = blockIdx.y * 64;
    const int t = threadIdx.x;
    const int lr = t >> 2, lk = (t & 3) * 4;
    float rm = 0.f, rv = 0.f;
    if constexpr (AMODE == 1) { rm = rowmu[r0 + lr]; rv = rowrs[r0 + lr]; }
    float acc[4][4] = {};
    const int tr = (t >> 4) * 4, tc = (t & 15) * 4;
    for (int k0 = 0; k0 < K; k0 += 16) {
        float a0, a1, a2, a3;
        if constexpr (AMODE == 2) {
            ushort4 u = *(const ushort4*)((const unsigned short*)Av + (size_t)(r0 + lr) * K + k0 + lk);
            a0 = bf2f(u.x); a1 = bf2f(u.y); a2 = bf2f(u.z); a3 = bf2f(u.w);
        } else {
            float4 av = *(const float4*)((const float*)Av + (size_t)(r0 + lr) * K + k0 + lk);
            a0 = av.x; a1 = av.y; a2 = av.z; a3 = av.w;
            if constexpr (AMODE == 1) {
                float4 cw = *(const float4*)(colw + k0 + lk);
                float4 cb = *(const float4*)(colb + k0 + lk);
                a0 = (a0 - rm) * rv * cw.x + cb.x;
                a1 = (a1 - rm) * rv * cw.y + cb.y;
                a2 = (a2 - rm) * rv * cw.z + cb.z;
                a3 = (a3 - rm) * rv * cw.w + cb.w;
            } else if constexpr (AMODE == 3) {
                float4 cw = *(const float4*)(colw + k0 + lk);
                float4 cb = *(const float4*)(colb + k0 + lk);
                a0 = fmaxf(a0 * cw.x + cb.x, 0.f);
                a1 = fmaxf(a1 * cw.y + cb.y, 0.f);
                a2 = fmaxf(a2 * cw.z + cb.z, 0.f);
                a3 = fmaxf(a3 * cw.w + cb.w, 0.f);
            }
        }
        As[lr][lk + 0] = a0; As[lr][lk + 1] = a1;
        As[lr][lk + 2] = a2; As[lr][lk + 3] = a3;
        float4 bv = *(const float4*)(Bw + (size_t)(c0 + lr) * K + k0 + lk);
        Bs[lk + 0][lr] = bv.x; Bs[lk + 1][lr] = bv.y;
        Bs[lk + 2][lr] = bv.z; Bs[lk + 3][lr] = bv.w;
        __syncthreads();
        #pragma unroll
        for (int kk = 0; kk < 16; kk++) {
            float a[4], b[4];
            #pragma unroll
            for (int i = 0; i < 4; i++) a[i] = As[tr + i][kk];
            #pragma unroll
            for (int j = 0; j < 4; j++) b[j] = Bs[kk][tc + j];
            #pragma unroll
            for (int i = 0; i < 4; i++)
                #pragma unroll
                for (int j = 0; j < 4; j++) acc[i][j] = fmaf(a[i], b[j], acc[i][j]);
        }
        __syncthreads();
    }
    #pragma unroll
    for (int i = 0; i < 4; i++) {
        int r = r0 + tr + i, c = c0 + tc;
        if constexpr (OMODE == 0) {
            ushort4 o;
            o.x = f2bf(acc[i][0]); o.y = f2bf(acc[i][1]);
            o.z = f2bf(acc[i][2]); o.w = f2bf(acc[i][3]);
            *(ushort4*)((unsigned short*)Outv + (size_t)r * CN + c) = o;
        } else {
            float4 bb = *(const float4*)(bias + c);
            float4 o;
            o.x = acc[i][0] + bb.x; o.y = acc[i][1] + bb.y;
            o.z = acc[i][2] + bb.z; o.w = acc[i][3] + bb.w;
            if constexpr (OMODE == 2) {
                float4 rr = *(const float4*)(resid + (size_t)r * CN + c);
                o.x += rr.x; o.y += rr.y; o.z += rr.z; o.w += rr.w;
            }
            *(float4*)((float*)Outv + (size_t)r * CN + c) = o;
        }
    }
}

// ---- windowed attention: one block per (window, head), 2 q-rows/thread ----
// K/V tile (256 rows) staged fp32 in LDS (64 KB); softmax without max-subtract
// (scores are O(0.1) here; exp overflow needs |s|>88).
__global__ __launch_bounds__(256, 2) void attn_k(
        const unsigned short* __restrict__ qkv, const int* __restrict__ widx,
        const int* __restrict__ wlen, unsigned short* __restrict__ aout) {
    extern __shared__ float smem[];
    float* Ks = smem;              // [256][32]
    float* Vs = smem + 256 * DHEAD;
    const int m = blockIdx.x >> 3, h = blockIdx.x & 7;
    const int t = threadIdx.x;
    const int len = wlen[m];
    float q0[DHEAD], q1[DHEAD], o0[DHEAD], o1[DHEAD];
    #pragma unroll
    for (int d = 0; d < DHEAD; d++) { o0[d] = 0.f; o1[d] = 0.f; }
    {
        int qr0 = widx[m * WWIN + t];
        int qr1 = widx[m * WWIN + t + 256];
        const uint4* p0 = (const uint4*)(qkv + (size_t)qr0 * 768 + h * DHEAD);
        const uint4* p1 = (const uint4*)(qkv + (size_t)qr1 * 768 + h * DHEAD);
        #pragma unroll
        for (int i = 0; i < 4; i++) { unpack8(p0[i], q0 + i * 8); unpack8(p1[i], q1 + i * 8); }
    }
    float l0 = 0.f, l1 = 0.f;
    for (int kt = 0; kt < WWIN; kt += 256) {
        __syncthreads();
        {
            int src = widx[m * WWIN + kt + t];
            const uint4* kp = (const uint4*)(qkv + (size_t)src * 768 + 256 + h * DHEAD);
            const uint4* vp = (const uint4*)(qkv + (size_t)src * 768 + 512 + h * DHEAD);
            float tmp[8];
            #pragma unroll
            for (int i = 0; i < 4; i++) {
                unpack8(kp[i], tmp);
                *(float4*)(Ks + t * DHEAD + i * 8)     = make_float4(tmp[0], tmp[1], tmp[2], tmp[3]);
                *(float4*)(Ks + t * DHEAD + i * 8 + 4) = make_float4(tmp[4], tmp[5], tmp[6], tmp[7]);
            }
            #pragma unroll
            for (int i = 0; i < 4; i++) {
                unpack8(vp[i], tmp);
                *(float4*)(Vs + t * DHEAD + i * 8)     = make_float4(tmp[0], tmp[1], tmp[2], tmp[3]);
                *(float4*)(Vs + t * DHEAD + i * 8 + 4) = make_float4(tmp[4], tmp[5], tmp[6], tmp[7]);
            }
        }
        __syncthreads();
        int klim = len - kt; if (klim > 256) klim = 256;
        for (int k = 0; k < klim; k++) {
            const float* kr = Ks + k * DHEAD;
            float s0 = 0.f, s1 = 0.f;
            #pragma unroll
            for (int d = 0; d < DHEAD; d++) {
                float kv = kr[d];
                s0 = fmaf(q0[d], kv, s0); s1 = fmaf(q1[d], kv, s1);
            }
            float e0 = __expf(s0 * 0.17677669529663687f);
            float e1 = __expf(s1 * 0.17677669529663687f);
            l0 += e0; l1 += e1;
            const float* vr = Vs + k * DHEAD;
            #pragma unroll
            for (int d = 0; d < DHEAD; d++) {
                float vv = vr[d];
                o0[d] = fmaf(e0, vv, o0[d]); o1[d] = fmaf(e1, vv, o1[d]);
            }
        }
    }
    float n0 = 1.f / l0, n1 = 1.f / l1;
    unsigned short* w0 = aout + ((size_t)m * WWIN + t) * C_DIM + h * DHEAD;
    unsigned short* w1 = aout + ((size_t)m * WWIN + t + 256) * C_DIM + h * DHEAD;
    #pragma unroll
    for (int i = 0; i < DHEAD; i += 4) {
        ushort4 a, b;
        a.x = f2bf(o0[i] * n0); a.y = f2bf(o0[i + 1] * n0);
        a.z = f2bf(o0[i + 2] * n0); a.w = f2bf(o0[i + 3] * n0);
        b.x = f2bf(o1[i] * n1); b.y = f2bf(o1[i + 1] * n1);
        b.z = f2bf(o1[i + 2] * n1); b.w = f2bf(o1[i + 3] * n1);
        *(ushort4*)(w0 + i) = a;
        *(ushort4*)(w1 + i) = b;
    }
}

// ---- combine: x1 = x + gathered(out_proj)/count, plus LN2 row stats ----
__global__ __launch_bounds__(256) void combine_k(
        const float* __restrict__ x, const float* __restrict__ proj,
        const int* __restrict__ cnt, const int* __restrict__ inv,
        float* __restrict__ x1, float* __restrict__ mu, float* __restrict__ rs) {
    int lane = threadIdx.x & 63;
    int row = blockIdx.x * 4 + (threadIdx.x >> 6);
    int c = cnt[row];
    if (c > 2) c = 2;
    float4 acc = make_float4(0.f, 0.f, 0.f, 0.f);
    for (int s = 0; s < c; s++) {
        int src = inv[row * 2 + s];
        float4 p = ((const float4*)(proj + (size_t)src * C_DIM))[lane];
        acc.x += p.x; acc.y += p.y; acc.z += p.z; acc.w += p.w;
    }
    float ic = 1.f / (float)(c > 0 ? c : 1);
    float4 xv = ((const float4*)(x + (size_t)row * C_DIM))[lane];
    float4 r4;
    r4.x = xv.x + acc.x * ic; r4.y = xv.y + acc.y * ic;
    r4.z = xv.z + acc.z * ic; r4.w = xv.w + acc.w * ic;
    ((float4*)(x1 + (size_t)row * C_DIM))[lane] = r4;
    float s = r4.x + r4.y + r4.z + r4.w;
    float q = r4.x * r4.x + r4.y * r4.y + r4.z * r4.z + r4.w * r4.w;
    #pragma unroll
    for (int o = 32; o; o >>= 1) { s += __shfl_xor(s, o); q += __shfl_xor(q, o); }
    if (lane == 0) {
        float mm = s * (1.f / C_DIM);
        float var = q * (1.f / C_DIM) - mm * mm;
        mu[row] = mm; rs[row] = rsqrtf(var + 1e-5f);
    }
}

// ---- BatchNorm stats over rows ----
__global__ __launch_bounds__(256) void bnpart_k(const float* __restrict__ h,
        float* __restrict__ hsum, float* __restrict__ hsq, int rows_per_block) {
    int r0 = blockIdx.x * rows_per_block;
    int t = threadIdx.x;
    float s0 = 0.f, q0 = 0.f, s1 = 0.f, q1 = 0.f;
    for (int r = r0; r < r0 + rows_per_block; r++) {
        float v0 = h[(size_t)r * HID_DIM + t];
        float v1 = h[(size_t)r * HID_DIM + t + 256];
        s0 += v0; q0 += v0 * v0; s1 += v1; q1 += v1 * v1;
    }
    atomicAdd(&hsum[t], s0); atomicAdd(&hsq[t], q0);
    atomicAdd(&hsum[t + 256], s1); atomicAdd(&hsq[t + 256], q1);
}

__global__ void bnfin_k(const float* __restrict__ hsum, const float* __restrict__ hsq,
        const float* __restrict__ bnw, const float* __restrict__ bnb,
        float* __restrict__ premul, float* __restrict__ preadd, float inv_n) {
    int c = threadIdx.x;
    float m = hsum[c] * inv_n;
    float var = hsq[c] * inv_n - m * m;
    float rstd = rsqrtf(var + 1e-5f);
    float pm = rstd * bnw[c];
    premul[c] = pm;
    preadd[c] = bnb[c] - m * pm;
}

extern "C" void kernel_launch(void* const* d_in, const int* in_sizes, int n_in,
                              void* d_out, int out_size, void* d_ws, size_t ws_size,
                              hipStream_t stream) {
    const float* x    = (const float*)d_in[0];
    const int* widx   = (const int*)d_in[1];
    // d_in[2] (win_mask) is reconstructed from win_idx; not read.
    const float* ln1w = (const float*)d_in[3];
    const float* ln1b = (const float*)d_in[4];
    const float* wqkv = (const float*)d_in[5];
    const float* wproj = (const float*)d_in[6];
    const float* bproj = (const float*)d_in[7];
    const float* ln2w = (const float*)d_in[8];
    const float* ln2b = (const float*)d_in[9];
    const float* w1   = (const float*)d_in[10];
    const float* b1   = (const float*)d_in[11];
    const float* bnw  = (const float*)d_in[12];
    const float* bnb  = (const float*)d_in[13];
    const float* w2   = (const float*)d_in[14];
    const float* b2   = (const float*)d_in[15];
    float* out = (float*)d_out;

    const int N  = in_sizes[0] / C_DIM;   // 25600
    const int MW = in_sizes[1];           // M * 512
    const int M  = MW / WWIN;             // 100

    char* w = (char*)d_ws;
    size_t off = 0;
    auto alloc = [&](size_t bytes) -> void* {
        void* p = w + off;
        off += (bytes + 255) & ~(size_t)255;
        return p;
    };
    // Region A (52.4 MB): qkv bf16 [N,768] -> out_proj f32 [MW,256] -> h f32 [N,512]
    size_t szA = (size_t)MW * C_DIM * 4;
    void* regA = alloc(szA);
    unsigned short* qkv = (unsigned short*)regA;
    float* out_proj = (float*)regA;
    float* hbuf = (float*)regA;
    // Region B (26.2 MB): attn_out bf16 [MW,256] -> x1 f32 [N,256]
    size_t szB = (size_t)MW * C_DIM * 2;
    void* regB = alloc(szB);
    unsigned short* attn_out = (unsigned short*)regB;
    float* x1 = (float*)regB;

    float* mu0 = (float*)alloc((size_t)N * 4);
    float* rs0 = (float*)alloc((size_t)N * 4);
    float* mu1 = (float*)alloc((size_t)N * 4);
    float* rs1 = (float*)alloc((size_t)N * 4);
    int* cnt   = (int*)alloc((size_t)N * 4);
    int* inv   = (int*)alloc((size_t)N * 8);
    int* wlen  = (int*)alloc((size_t)M * 4);
    float* hsum = (float*)alloc(HID_DIM * 4);
    float* hsq  = (float*)alloc(HID_DIM * 4);
    float* premul = (float*)alloc(HID_DIM * 4);
    float* preadd = (float*)alloc(HID_DIM * 4);

    hipMemsetAsync(cnt, 0, (size_t)N * 4, stream);
    hipMemsetAsync(hsum, 0, HID_DIM * 4, stream);
    hipMemsetAsync(hsq, 0, HID_DIM * 4, stream);

    // 1. LN1 row stats
    rowstats_k<<<N / 4, 256, 0, stream>>>(x, mu0, rs0);
    // 2. window lengths + inverse map
    wininv_k<<<M, 512, 0, stream>>>(widx, wlen, cnt, inv);
    // 3. QKV = LN1(x) @ w_qkv^T  (per-token, gather commutes)
    gemm_k<256, 1, 0><<<dim3(768 / 64, N / 64), 256, 0, stream>>>(
        x, wqkv, nullptr, qkv, mu0, rs0, ln1w, ln1b, nullptr, 768);
    // 4. windowed attention
    attn_k<<<M * NHEAD, 256, 65536, stream>>>(qkv, widx, wlen, attn_out);
    // 5. out_proj = attn @ w_proj^T + b_proj
    gemm_k<256, 2, 1><<<dim3(256 / 64, MW / 64), 256, 0, stream>>>(
        attn_out, wproj, bproj, out_proj, nullptr, nullptr, nullptr, nullptr, nullptr, 256);
    // 6. x1 = x + gather(out_proj)/count ; LN2 row stats
    combine_k<<<N / 4, 256, 0, stream>>>(x, out_proj, cnt, inv, x1, mu1, rs1);
    // 7. h = LN2(x1) @ w1^T + b1
    gemm_k<256, 1, 1><<<dim3(512 / 64, N / 64), 256, 0, stream>>>(
        x1, w1, b1, hbuf, mu1, rs1, ln2w, ln2b, nullptr, 512);
    // 8. BatchNorm stats
    bnpart_k<<<N / 128, 256, 0, stream>>>(hbuf, hsum, hsq, 128);
    bnfin_k<<<1, HID_DIM, 0, stream>>>(hsum, hsq, bnw, bnb, premul, preadd, 1.0f / (float)N);
    // 9. out = x1 + relu(BN(h)) @ w2^T + b2
    gemm_k<512, 3, 2><<<dim3(256 / 64, N / 64), 256, 0, stream>>>(
        hbuf, w2, b2, out, nullptr, nullptr, premul, preadd, x1, 256);
}

// Round 2
// 723.606 us; speedup vs baseline: 2.1777x; 2.1777x over previous
//
#include <hip/hip_runtime.h>

#define C_DIM 256
#define HID_DIM 512
#define NHEAD 8
#define DHEAD 32
#define WWIN 512

typedef __attribute__((ext_vector_type(8))) short frag_ab;   // 8 bf16
typedef __attribute__((ext_vector_type(4))) float f32x4;

__device__ __forceinline__ float bf2f(unsigned int u16) {
    return __uint_as_float(u16 << 16);
}
__device__ __forceinline__ unsigned short f2bf(float f) {
    unsigned int x = __float_as_uint(f);
    return (unsigned short)((x + 0x7fffu + ((x >> 16) & 1u)) >> 16);
}
__device__ __forceinline__ void unpack8(uint4 u, float* d) {
    d[0] = bf2f(u.x & 0xffffu); d[1] = bf2f(u.x >> 16);
    d[2] = bf2f(u.y & 0xffffu); d[3] = bf2f(u.y >> 16);
    d[4] = bf2f(u.z & 0xffffu); d[5] = bf2f(u.z >> 16);
    d[6] = bf2f(u.w & 0xffffu); d[7] = bf2f(u.w >> 16);
}
// pack two f32 into two truncated bf16 in one v_perm
__device__ __forceinline__ unsigned int pk2(float lo, float hi) {
    return __builtin_amdgcn_perm(__float_as_uint(hi), __float_as_uint(lo), 0x07060302u);
}

// ---- per-row LayerNorm stats: one wave per row of 256 floats ----
__global__ __launch_bounds__(256) void rowstats_k(const float* __restrict__ X,
        float* __restrict__ mu, float* __restrict__ rs) {
    int lane = threadIdx.x & 63;
    int row = blockIdx.x * 4 + (threadIdx.x >> 6);
    float4 v = ((const float4*)(X + (size_t)row * C_DIM))[lane];
    float s = v.x + v.y + v.z + v.w;
    float q = v.x * v.x + v.y * v.y + v.z * v.z + v.w * v.w;
    #pragma unroll
    for (int o = 32; o; o >>= 1) { s += __shfl_xor(s, o); q += __shfl_xor(q, o); }
    if (lane == 0) {
        float m = s * (1.0f / C_DIM);
        float var = q * (1.0f / C_DIM) - m * m;
        mu[row] = m; rs[row] = rsqrtf(var + 1e-5f);
    }
}

// ---- window valid-lengths + inverse (token -> (window,offset)) map ----
__global__ __launch_bounds__(512) void wininv_k(const int* __restrict__ widx,
        int* __restrict__ wlen, int* __restrict__ cnt, int* __restrict__ inv) {
    int m = blockIdx.x, j = threadIdx.x;
    int id = widx[m * WWIN + j];
    int valid = (j == 0) || (id != widx[m * WWIN + j - 1]);
    __shared__ int part[8];
    int v = valid;
    #pragma unroll
    for (int o = 32; o; o >>= 1) v += __shfl_xor(v, o);
    if ((j & 63) == 0) part[j >> 6] = v;
    __syncthreads();
    if (j == 0) {
        int s = 0;
        #pragma unroll
        for (int i = 0; i < 8; i++) s += part[i];
        wlen[m] = s;
    }
    if (valid) {
        int slot = atomicAdd(&cnt[id], 1);
        if (slot < 2) inv[id * 2 + slot] = m * WWIN + j;
    }
}

// ---- generic tiled fp32 GEMM: out[r][c] = act(sum_k At(r,k)*B[c][k]) ----
template<int K, int AMODE, int OMODE>
__global__ __launch_bounds__(256, 4) void gemm_k(
        const void* __restrict__ Av, const float* __restrict__ Bw,
        const float* __restrict__ bias, void* __restrict__ Outv,
        const float* __restrict__ rowmu, const float* __restrict__ rowrs,
        const float* __restrict__ colw, const float* __restrict__ colb,
        const float* __restrict__ resid, int CN) {
    __shared__ float As[64][17];
    __shared__ float Bs[16][64];
    const int c0 = blockIdx.x * 64, r0 = blockIdx.y * 64;
    const int t = threadIdx.x;
    const int lr = t >> 2, lk = (t & 3) * 4;
    float rm = 0.f, rv = 0.f;
    if constexpr (AMODE == 1) { rm = rowmu[r0 + lr]; rv = rowrs[r0 + lr]; }
    float acc[4][4] = {};
    const int tr = (t >> 4) * 4, tc = (t & 15) * 4;
    for (int k0 = 0; k0 < K; k0 += 16) {
        float a0, a1, a2, a3;
        if constexpr (AMODE == 2) {
            ushort4 u = *(const ushort4*)((const unsigned short*)Av + (size_t)(r0 + lr) * K + k0 + lk);
            a0 = bf2f(u.x); a1 = bf2f(u.y); a2 = bf2f(u.z); a3 = bf2f(u.w);
        } else {
            float4 av = *(const float4*)((const float*)Av + (size_t)(r0 + lr) * K + k0 + lk);
            a0 = av.x; a1 = av.y; a2 = av.z; a3 = av.w;
            if constexpr (AMODE == 1) {
                float4 cw = *(const float4*)(colw + k0 + lk);
                float4 cb = *(const float4*)(colb + k0 + lk);
                a0 = (a0 - rm) * rv * cw.x + cb.x;
                a1 = (a1 - rm) * rv * cw.y + cb.y;
                a2 = (a2 - rm) * rv * cw.z + cb.z;
                a3 = (a3 - rm) * rv * cw.w + cb.w;
            } else if constexpr (AMODE == 3) {
                float4 cw = *(const float4*)(colw + k0 + lk);
                float4 cb = *(const float4*)(colb + k0 + lk);
                a0 = fmaxf(a0 * cw.x + cb.x, 0.f);
                a1 = fmaxf(a1 * cw.y + cb.y, 0.f);
                a2 = fmaxf(a2 * cw.z + cb.z, 0.f);
                a3 = fmaxf(a3 * cw.w + cb.w, 0.f);
            }
        }
        As[lr][lk + 0] = a0; As[lr][lk + 1] = a1;
        As[lr][lk + 2] = a2; As[lr][lk + 3] = a3;
        float4 bv = *(const float4*)(Bw + (size_t)(c0 + lr) * K + k0 + lk);
        Bs[lk + 0][lr] = bv.x; Bs[lk + 1][lr] = bv.y;
        Bs[lk + 2][lr] = bv.z; Bs[lk + 3][lr] = bv.w;
        __syncthreads();
        #pragma unroll
        for (int kk = 0; kk < 16; kk++) {
            float a[4], b[4];
            #pragma unroll
            for (int i = 0; i < 4; i++) a[i] = As[tr + i][kk];
            #pragma unroll
            for (int j = 0; j < 4; j++) b[j] = Bs[kk][tc + j];
            #pragma unroll
            for (int i = 0; i < 4; i++)
                #pragma unroll
                for (int j = 0; j < 4; j++) acc[i][j] = fmaf(a[i], b[j], acc[i][j]);
        }
        __syncthreads();
    }
    #pragma unroll
    for (int i = 0; i < 4; i++) {
        int r = r0 + tr + i, c = c0 + tc;
        if constexpr (OMODE == 0) {
            ushort4 o;
            o.x = f2bf(acc[i][0]); o.y = f2bf(acc[i][1]);
            o.z = f2bf(acc[i][2]); o.w = f2bf(acc[i][3]);
            *(ushort4*)((unsigned short*)Outv + (size_t)r * CN + c) = o;
        } else {
            float4 bb = *(const float4*)(bias + c);
            float4 o;
            o.x = acc[i][0] + bb.x; o.y = acc[i][1] + bb.y;
            o.z = acc[i][2] + bb.z; o.w = acc[i][3] + bb.w;
            if constexpr (OMODE == 2) {
                float4 rr = *(const float4*)(resid + (size_t)r * CN + c);
                o.x += rr.x; o.y += rr.y; o.z += rr.z; o.w += rr.w;
            }
            *(float4*)((float*)Outv + (size_t)r * CN + c) = o;
        }
    }
}

// ---- MFMA windowed attention ----
// Block = (window m, head h), 4 waves, wave w owns q rows w*128..w*128+127.
// S^T = K·Q^T (per 32-krow sub-chunk), exp via exp2f (Q pre-scaled by
// scale*log2e), P round-trips through per-wave LDS (C-layout b64 writes ->
// B-fragment b128 reads, intra-wave, no barrier), O^T = V^T·P^T.
#define PSTR 40    // P row stride (bf16): 32 + 8 pad -> balanced banks
#define VSTR 136   // V^T row stride (bf16): 128 + 8 pad
__global__ __launch_bounds__(256, 2) void attn_mfma_k(
        const unsigned short* __restrict__ qkv, const int* __restrict__ widx,
        const int* __restrict__ wlen, unsigned short* __restrict__ aout) {
    __shared__ unsigned short Kl[128 * 32];
    __shared__ unsigned short Vt[32 * VSTR];
    __shared__ unsigned short Pl[4][128 * PSTR];
    const int m = blockIdx.x >> 3, h = blockIdx.x & 7;
    const int t = threadIdx.x;
    const int w = t >> 6;
    const int lane = t & 63;
    const int Q = lane >> 4, n = lane & 15;
    const int len = wlen[m];
    const int* wrow = widx + m * WWIN;
    unsigned short* Pw = Pl[w];
    const f32x4 z4 = {0.f, 0.f, 0.f, 0.f};

    // Q fragments (8 q-tiles), pre-scaled by 1/sqrt(DH) * log2(e)
    const float qs = 0.17677669529663687f * 1.4426950408889634f;
    frag_ab qf[8];
    #pragma unroll
    for (int qt = 0; qt < 8; qt++) {
        int q = w * 128 + qt * 16 + n;
        int tok = wrow[q];
        uint4 u = *(const uint4*)(qkv + (size_t)tok * 768 + h * DHEAD + Q * 8);
        float f[8]; unpack8(u, f);
        uint4 r;
        r.x = pk2(f[0] * qs, f[1] * qs); r.y = pk2(f[2] * qs, f[3] * qs);
        r.z = pk2(f[4] * qs, f[5] * qs); r.w = pk2(f[6] * qs, f[7] * qs);
        qf[qt] = __builtin_bit_cast(frag_ab, r);
    }

    f32x4 Ot[2][8];
    #pragma unroll
    for (int dt = 0; dt < 2; dt++)
        #pragma unroll
        for (int qt = 0; qt < 8; qt++) Ot[dt][qt] = z4;
    float rsum[8] = {0.f, 0.f, 0.f, 0.f, 0.f, 0.f, 0.f, 0.f};

    const int nchunk = (len + 127) >> 7;
    for (int c = 0; c < nchunk; c++) {
        const int kb = c << 7;
        __syncthreads();
        if (t < 128) {                       // stage V^T (transposed scatter)
            int r = t;
            int tok = wrow[kb + r];
            const uint4* src = (const uint4*)(qkv + (size_t)tok * 768 + 512 + h * DHEAD);
            #pragma unroll
            for (int i = 0; i < 4; i++) {
                uint4 u = src[i];
                unsigned short* vp = &Vt[(i * 8) * VSTR + r];
                vp[0 * VSTR] = (unsigned short)(u.x & 0xffffu);
                vp[1 * VSTR] = (unsigned short)(u.x >> 16);
                vp[2 * VSTR] = (unsigned short)(u.y & 0xffffu);
                vp[3 * VSTR] = (unsigned short)(u.y >> 16);
                vp[4 * VSTR] = (unsigned short)(u.z & 0xffffu);
                vp[5 * VSTR] = (unsigned short)(u.z >> 16);
                vp[6 * VSTR] = (unsigned short)(u.w & 0xffffu);
                vp[7 * VSTR] = (unsigned short)(u.w >> 16);
            }
        } else {                             // stage K rows (rotated for banks)
            int r = t - 128;
            int tok = wrow[kb + r];
            const uint4* src = (const uint4*)(qkv + (size_t)tok * 768 + 256 + h * DHEAD);
            #pragma unroll
            for (int i = 0; i < 4; i++) {
                int c4 = (r + i) & 3;
                *(uint4*)&Kl[r * 32 + c4 * 8] = src[c4];
            }
        }
        __syncthreads();
        int rem = len - kb; if (rem > 128) rem = 128;
        const int nsub = (rem + 31) >> 5;
        for (int s = 0; s < nsub; s++) {
            const int lim = rem - s * 32;          // >=32 unless partial tail
            frag_ab kf0 = *(const frag_ab*)&Kl[(s * 32 + n) * 32 + Q * 8];
            frag_ab kf1 = *(const frag_ab*)&Kl[(s * 32 + 16 + n) * 32 + Q * 8];
            #pragma unroll
            for (int qt = 0; qt < 8; qt++) {
                f32x4 s0 = __builtin_amdgcn_mfma_f32_16x16x32_bf16(kf0, qf[qt], z4, 0, 0, 0);
                f32x4 s1 = __builtin_amdgcn_mfma_f32_16x16x32_bf16(kf1, qf[qt], z4, 0, 0, 0);
                float e[8];
                #pragma unroll
                for (int i = 0; i < 4; i++) {
                    e[i]     = exp2f(s0[i]);
                    e[4 + i] = exp2f(s1[i]);
                }
                if (lim < 32) {
                    #pragma unroll
                    for (int i = 0; i < 4; i++) {
                        if (4 * Q + i >= lim)      e[i] = 0.f;
                        if (16 + 4 * Q + i >= lim) e[4 + i] = 0.f;
                    }
                }
                float rsq = rsum[qt];
                #pragma unroll
                for (int i = 0; i < 8; i++) rsq += e[i];
                rsum[qt] = rsq;
                uint2 p0, p1;
                p0.x = pk2(e[0], e[1]); p0.y = pk2(e[2], e[3]);
                p1.x = pk2(e[4], e[5]); p1.y = pk2(e[6], e[7]);
                *(uint2*)&Pw[(qt * 16 + n) * PSTR + 4 * Q]      = p0;
                *(uint2*)&Pw[(qt * 16 + n) * PSTR + 16 + 4 * Q] = p1;
            }
            asm volatile("s_waitcnt lgkmcnt(0)" ::: "memory");
            frag_ab vf0 = *(const frag_ab*)&Vt[n * VSTR + s * 32 + Q * 8];
            frag_ab vf1 = *(const frag_ab*)&Vt[(16 + n) * VSTR + s * 32 + Q * 8];
            #pragma unroll
            for (int qt = 0; qt < 8; qt++) {
                frag_ab pf = *(const frag_ab*)&Pw[(qt * 16 + n) * PSTR + Q * 8];
                Ot[0][qt] = __builtin_amdgcn_mfma_f32_16x16x32_bf16(vf0, pf, Ot[0][qt], 0, 0, 0);
                Ot[1][qt] = __builtin_amdgcn_mfma_f32_16x16x32_bf16(vf1, pf, Ot[1][qt], 0, 0, 0);
            }
        }
    }

    #pragma unroll
    for (int qt = 0; qt < 8; qt++) {
        float r = rsum[qt];
        r += __shfl_xor(r, 16);
        r += __shfl_xor(r, 32);
        float inv = 1.f / r;
        int q = w * 128 + qt * 16 + n;
        unsigned short* dst = aout + ((size_t)(m * WWIN + q)) * C_DIM + h * DHEAD;
        #pragma unroll
        for (int dt = 0; dt < 2; dt++) {
            f32x4 o = Ot[dt][qt];
            uint2 pk;
            pk.x = pk2(o[0] * inv, o[1] * inv);
            pk.y = pk2(o[2] * inv, o[3] * inv);
            *(uint2*)(dst + dt * 16 + 4 * Q) = pk;
        }
    }
}

// ---- combine: x1 = x + gathered(out_proj)/count, plus LN2 row stats ----
__global__ __launch_bounds__(256) void combine_k(
        const float* __restrict__ x, const float* __restrict__ proj,
        const int* __restrict__ cnt, const int* __restrict__ inv,
        float* __restrict__ x1, float* __restrict__ mu, float* __restrict__ rs) {
    int lane = threadIdx.x & 63;
    int row = blockIdx.x * 4 + (threadIdx.x >> 6);
    int c = cnt[row];
    if (c > 2) c = 2;
    float4 acc = make_float4(0.f, 0.f, 0.f, 0.f);
    for (int s = 0; s < c; s++) {
        int src = inv[row * 2 + s];
        float4 p = ((const float4*)(proj + (size_t)src * C_DIM))[lane];
        acc.x += p.x; acc.y += p.y; acc.z += p.z; acc.w += p.w;
    }
    float ic = 1.f / (float)(c > 0 ? c : 1);
    float4 xv = ((const float4*)(x + (size_t)row * C_DIM))[lane];
    float4 r4;
    r4.x = xv.x + acc.x * ic; r4.y = xv.y + acc.y * ic;
    r4.z = xv.z + acc.z * ic; r4.w = xv.w + acc.w * ic;
    ((float4*)(x1 + (size_t)row * C_DIM))[lane] = r4;
    float s = r4.x + r4.y + r4.z + r4.w;
    float q = r4.x * r4.x + r4.y * r4.y + r4.z * r4.z + r4.w * r4.w;
    #pragma unroll
    for (int o = 32; o; o >>= 1) { s += __shfl_xor(s, o); q += __shfl_xor(q, o); }
    if (lane == 0) {
        float mm = s * (1.f / C_DIM);
        float var = q * (1.f / C_DIM) - mm * mm;
        mu[row] = mm; rs[row] = rsqrtf(var + 1e-5f);
    }
}

// ---- BatchNorm stats over rows ----
__global__ __launch_bounds__(256) void bnpart_k(const float* __restrict__ h,
        float* __restrict__ hsum, float* __restrict__ hsq, int rows_per_block) {
    int r0 = blockIdx.x * rows_per_block;
    int t = threadIdx.x;
    float s0 = 0.f, q0 = 0.f, s1 = 0.f, q1 = 0.f;
    for (int r = r0; r < r0 + rows_per_block; r++) {
        float v0 = h[(size_t)r * HID_DIM + t];
        float v1 = h[(size_t)r * HID_DIM + t + 256];
        s0 += v0; q0 += v0 * v0; s1 += v1; q1 += v1 * v1;
    }
    atomicAdd(&hsum[t], s0); atomicAdd(&hsq[t], q0);
    atomicAdd(&hsum[t + 256], s1); atomicAdd(&hsq[t + 256], q1);
}

__global__ void bnfin_k(const float* __restrict__ hsum, const float* __restrict__ hsq,
        const float* __restrict__ bnw, const float* __restrict__ bnb,
        float* __restrict__ premul, float* __restrict__ preadd, float inv_n) {
    int c = threadIdx.x;
    float m = hsum[c] * inv_n;
    float var = hsq[c] * inv_n - m * m;
    float rstd = rsqrtf(var + 1e-5f);
    float pm = rstd * bnw[c];
    premul[c] = pm;
    preadd[c] = bnb[c] - m * pm;
}

extern "C" void kernel_launch(void* const* d_in, const int* in_sizes, int n_in,
                              void* d_out, int out_size, void* d_ws, size_t ws_size,
                              hipStream_t stream) {
    const float* x    = (const float*)d_in[0];
    const int* widx   = (const int*)d_in[1];
    const float* ln1w = (const float*)d_in[3];
    const float* ln1b = (const float*)d_in[4];
    const float* wqkv = (const float*)d_in[5];
    const float* wproj = (const float*)d_in[6];
    const float* bproj = (const float*)d_in[7];
    const float* ln2w = (const float*)d_in[8];
    const float* ln2b = (const float*)d_in[9];
    const float* w1   = (const float*)d_in[10];
    const float* b1   = (const float*)d_in[11];
    const float* bnw  = (const float*)d_in[12];
    const float* bnb  = (const float*)d_in[13];
    const float* w2   = (const float*)d_in[14];
    const float* b2   = (const float*)d_in[15];
    float* out = (float*)d_out;

    const int N  = in_sizes[0] / C_DIM;   // 25600
    const int MW = in_sizes[1];           // M * 512
    const int M  = MW / WWIN;             // 100

    char* w = (char*)d_ws;
    size_t off = 0;
    auto alloc = [&](size_t bytes) -> void* {
        void* p = w + off;
        off += (bytes + 255) & ~(size_t)255;
        return p;
    };
    // Region A: qkv bf16 [N,768] -> out_proj f32 [MW,256] -> h f32 [N,512]
    size_t szA = (size_t)MW * C_DIM * 4;
    void* regA = alloc(szA);
    unsigned short* qkv = (unsigned short*)regA;
    float* out_proj = (float*)regA;
    float* hbuf = (float*)regA;
    // Region B: attn_out bf16 [MW,256] -> x1 f32 [N,256]
    size_t szB = (size_t)MW * C_DIM * 2;
    void* regB = alloc(szB);
    unsigned short* attn_out = (unsigned short*)regB;
    float* x1 = (float*)regB;

    float* mu0 = (float*)alloc((size_t)N * 4);
    float* rs0 = (float*)alloc((size_t)N * 4);
    float* mu1 = (float*)alloc((size_t)N * 4);
    float* rs1 = (float*)alloc((size_t)N * 4);
    int* cnt   = (int*)alloc((size_t)N * 4);
    int* inv   = (int*)alloc((size_t)N * 8);
    int* wlen  = (int*)alloc((size_t)M * 4);
    float* hsum = (float*)alloc(HID_DIM * 4);
    float* hsq  = (float*)alloc(HID_DIM * 4);
    float* premul = (float*)alloc(HID_DIM * 4);
    float* preadd = (float*)alloc(HID_DIM * 4);

    hipMemsetAsync(cnt, 0, (size_t)N * 4, stream);
    hipMemsetAsync(hsum, 0, HID_DIM * 4, stream);
    hipMemsetAsync(hsq, 0, HID_DIM * 4, stream);

    rowstats_k<<<N / 4, 256, 0, stream>>>(x, mu0, rs0);
    wininv_k<<<M, 512, 0, stream>>>(widx, wlen, cnt, inv);
    gemm_k<256, 1, 0><<<dim3(768 / 64, N / 64), 256, 0, stream>>>(
        x, wqkv, nullptr, qkv, mu0, rs0, ln1w, ln1b, nullptr, 768);
    attn_mfma_k<<<M * NHEAD, 256, 0, stream>>>(qkv, widx, wlen, attn_out);
    gemm_k<256, 2, 1><<<dim3(256 / 64, MW / 64), 256, 0, stream>>>(
        attn_out, wproj, bproj, out_proj, nullptr, nullptr, nullptr, nullptr, nullptr, 256);
    combine_k<<<N / 4, 256, 0, stream>>>(x, out_proj, cnt, inv, x1, mu1, rs1);
    gemm_k<256, 1, 1><<<dim3(512 / 64, N / 64), 256, 0, stream>>>(
        x1, w1, b1, hbuf, mu1, rs1, ln2w, ln2b, nullptr, 512);
    bnpart_k<<<N / 128, 256, 0, stream>>>(hbuf, hsum, hsq, 128);
    bnfin_k<<<1, HID_DIM, 0, stream>>>(hsum, hsq, bnw, bnb, premul, preadd, 1.0f / (float)N);
    gemm_k<512, 3, 2><<<dim3(256 / 64, N / 64), 256, 0, stream>>>(
        hbuf, w2, b2, out, nullptr, nullptr, premul, preadd, x1, 256);
}

// Round 3
// 346.190 us; speedup vs baseline: 4.5518x; 2.0902x over previous
//
#include <hip/hip_runtime.h>

#define C_DIM 256
#define HID_DIM 512
#define NHEAD 8
#define DHEAD 32
#define WWIN 512

typedef __attribute__((ext_vector_type(8))) short frag_ab;   // 8 bf16
typedef __attribute__((ext_vector_type(4))) float f32x4;

__device__ __forceinline__ float bf2f(unsigned int u16) {
    return __uint_as_float(u16 << 16);
}
__device__ __forceinline__ unsigned short f2bf(float f) {
    unsigned int x = __float_as_uint(f);
    return (unsigned short)((x + 0x7fffu + ((x >> 16) & 1u)) >> 16);
}
__device__ __forceinline__ void unpack8(uint4 u, float* d) {
    d[0] = bf2f(u.x & 0xffffu); d[1] = bf2f(u.x >> 16);
    d[2] = bf2f(u.y & 0xffffu); d[3] = bf2f(u.y >> 16);
    d[4] = bf2f(u.z & 0xffffu); d[5] = bf2f(u.z >> 16);
    d[6] = bf2f(u.w & 0xffffu); d[7] = bf2f(u.w >> 16);
}
// pack two f32 into two rounded bf16 in one v_perm
__device__ __forceinline__ unsigned int pk2(float lo, float hi) {
    return __builtin_amdgcn_perm(__float_as_uint(hi), __float_as_uint(lo), 0x07060302u);
}
// async 16B global->LDS (dest = uniform base + lane*16)
__device__ __forceinline__ void async_cp16(const void* g, void* l) {
    __builtin_amdgcn_global_load_lds(
        (const __attribute__((address_space(1))) unsigned int*)g,
        (__attribute__((address_space(3))) unsigned int*)l, 16, 0, 0);
}

// ---- per-row LayerNorm stats: one wave per row of 256 floats ----
__global__ __launch_bounds__(256) void rowstats_k(const float* __restrict__ X,
        float* __restrict__ mu, float* __restrict__ rs) {
    int lane = threadIdx.x & 63;
    int row = blockIdx.x * 4 + (threadIdx.x >> 6);
    float4 v = ((const float4*)(X + (size_t)row * C_DIM))[lane];
    float s = v.x + v.y + v.z + v.w;
    float q = v.x * v.x + v.y * v.y + v.z * v.z + v.w * v.w;
    #pragma unroll
    for (int o = 32; o; o >>= 1) { s += __shfl_xor(s, o); q += __shfl_xor(q, o); }
    if (lane == 0) {
        float m = s * (1.0f / C_DIM);
        float var = q * (1.0f / C_DIM) - m * m;
        mu[row] = m; rs[row] = rsqrtf(var + 1e-5f);
    }
}

// ---- window valid-lengths + inverse (token -> (window,offset)) map ----
__global__ __launch_bounds__(512) void wininv_k(const int* __restrict__ widx,
        int* __restrict__ wlen, int* __restrict__ cnt, int* __restrict__ inv) {
    int m = blockIdx.x, j = threadIdx.x;
    int id = widx[m * WWIN + j];
    int valid = (j == 0) || (id != widx[m * WWIN + j - 1]);
    __shared__ int part[8];
    int v = valid;
    #pragma unroll
    for (int o = 32; o; o >>= 1) v += __shfl_xor(v, o);
    if ((j & 63) == 0) part[j >> 6] = v;
    __syncthreads();
    if (j == 0) {
        int s = 0;
        #pragma unroll
        for (int i = 0; i < 8; i++) s += part[i];
        wlen[m] = s;
    }
    if (valid) {
        int slot = atomicAdd(&cnt[id], 1);
        if (slot < 2) inv[id * 2 + slot] = m * WWIN + j;
    }
}

// ---- convert the four weight matrices fp32 -> bf16 (one dispatch) ----
__global__ __launch_bounds__(256) void cvtw_k(
        const float* __restrict__ a, const float* __restrict__ b,
        const float* __restrict__ c, const float* __restrict__ d,
        unsigned short* __restrict__ oa, unsigned short* __restrict__ ob,
        unsigned short* __restrict__ oc, unsigned short* __restrict__ od) {
    int bi = blockIdx.x;
    const float* src; unsigned short* dst; int base;
    if (bi < 192)      { src = a; dst = oa; base = bi; }        // w_qkv 768x256
    else if (bi < 256) { src = b; dst = ob; base = bi - 192; }  // w_proj 256x256
    else if (bi < 384) { src = c; dst = oc; base = bi - 256; }  // w1 512x256
    else               { src = d; dst = od; base = bi - 384; }  // w2 256x512
    int i = base * 1024 + threadIdx.x * 4;
    float4 v = *(const float4*)(src + i);
    ushort4 o;
    o.x = f2bf(v.x); o.y = f2bf(v.y); o.z = f2bf(v.z); o.w = f2bf(v.w);
    *(ushort4*)(dst + i) = o;
}

// ---- MFMA GEMM: out[M,CN] = act_in(A[M,K]) @ Bw[CN,K]^T (+post-ops) ----
// 128x128 tile, BK=32, 4 waves each owning a 64x64 quadrant (4x4 MFMA tiles).
// LDS fragment layout uses XOR swizzle sub' = (sub + row/2)&3 so both the
// ds_write_b128 staging and ds_read_b128 fragment loads are bank-conflict-free.
// AMODE: 0 = bf16 A via global_load_lds
//        1 = fp32 A, fused LayerNorm: (a-rowmu)*rowrs*colw[k]+colb[k]
//        3 = fp32 A, fused BN+ReLU:   relu(a*colw[k]+colb[k])
// OMODE: 0 = bf16 store; 1 = bf16 store + bias; 2 = fp32 + bias;
//        3 = fp32 + bias + column stats atomics (hsum/hsq);
//        4 = fp32 + bias + resid
template<int K, int AMODE, int OMODE>
__global__ __launch_bounds__(256, 2) void mgemm_k(
        const void* __restrict__ Av, const unsigned short* __restrict__ Bw,
        const float* __restrict__ bias, void* __restrict__ Outv,
        const float* __restrict__ rowmu, const float* __restrict__ rowrs,
        const float* __restrict__ colw, const float* __restrict__ colb,
        const float* __restrict__ resid, float* __restrict__ hsum,
        float* __restrict__ hsq, int CN) {
    __shared__ unsigned short As[4096];   // 128 rows x 4 slots x 8 bf16
    __shared__ unsigned short Bs[4096];
    const int t = threadIdx.x;
    const int w = t >> 6, lane = t & 63;
    const int Q = lane >> 4, n = lane & 15;
    const int r0 = blockIdx.y * 128, c0 = blockIdx.x * 128;
    const int qr0 = (w & 1) * 64, qc0 = (w >> 1) * 64;
    const f32x4 z4 = {0.f, 0.f, 0.f, 0.f};
    f32x4 acc[4][4];
    #pragma unroll
    for (int i = 0; i < 4; i++)
        #pragma unroll
        for (int j = 0; j < 4; j++) acc[i][j] = z4;

    for (int k0 = 0; k0 < K; k0 += 32) {
        if (k0) __syncthreads();
        // ---- stage B (async, swizzled dest order) ----
        #pragma unroll
        for (int i = 0; i < 2; i++) {
            int sbase = w * 128 + i * 64;
            int l = sbase + lane;
            int col = l >> 2;
            int sub = ((l & 3) - (col >> 1)) & 3;
            async_cp16(Bw + (size_t)(c0 + col) * K + k0 + sub * 8, &Bs[sbase * 8]);
        }
        // ---- stage A ----
        if constexpr (AMODE == 0) {
            #pragma unroll
            for (int i = 0; i < 2; i++) {
                int sbase = w * 128 + i * 64;
                int l = sbase + lane;
                int row = l >> 2;
                int sub = ((l & 3) - (row >> 1)) & 3;
                async_cp16((const unsigned short*)Av + (size_t)(r0 + row) * K + k0 + sub * 8,
                           &As[sbase * 8]);
            }
        } else {
            #pragma unroll
            for (int ii = 0; ii < 2; ii++) {
                int s = t + ii * 256;
                int row = s >> 2;
                int sub = ((s & 3) - (row >> 1)) & 3;
                const float* src = (const float*)Av + (size_t)(r0 + row) * K + k0 + sub * 8;
                float4 v0 = ((const float4*)src)[0];
                float4 v1 = ((const float4*)src)[1];
                float f[8] = {v0.x, v0.y, v0.z, v0.w, v1.x, v1.y, v1.z, v1.w};
                float4 cw0 = *(const float4*)(colw + k0 + sub * 8);
                float4 cw1 = *(const float4*)(colw + k0 + sub * 8 + 4);
                float4 cb0 = *(const float4*)(colb + k0 + sub * 8);
                float4 cb1 = *(const float4*)(colb + k0 + sub * 8 + 4);
                float cw[8] = {cw0.x, cw0.y, cw0.z, cw0.w, cw1.x, cw1.y, cw1.z, cw1.w};
                float cb[8] = {cb0.x, cb0.y, cb0.z, cb0.w, cb1.x, cb1.y, cb1.z, cb1.w};
                if constexpr (AMODE == 1) {
                    float rm = rowmu[r0 + row], rv = rowrs[r0 + row];
                    #pragma unroll
                    for (int j = 0; j < 8; j++) f[j] = (f[j] - rm) * rv * cw[j] + cb[j];
                } else {
                    #pragma unroll
                    for (int j = 0; j < 8; j++) f[j] = fmaxf(f[j] * cw[j] + cb[j], 0.f);
                }
                uint4 pkd;
                pkd.x = pk2(f[0], f[1]); pkd.y = pk2(f[2], f[3]);
                pkd.z = pk2(f[4], f[5]); pkd.w = pk2(f[6], f[7]);
                *(uint4*)&As[s * 8] = pkd;
            }
        }
        asm volatile("s_waitcnt vmcnt(0)" ::: "memory");
        __syncthreads();
        // ---- compute ----
        const int asub = (Q + (n >> 1)) & 3;
        frag_ab af[4], bfr[4];
        #pragma unroll
        for (int i = 0; i < 4; i++) {
            af[i]  = *(const frag_ab*)&As[((qr0 + i * 16 + n) * 4 + asub) * 8];
            bfr[i] = *(const frag_ab*)&Bs[((qc0 + i * 16 + n) * 4 + asub) * 8];
        }
        #pragma unroll
        for (int rt = 0; rt < 4; rt++)
            #pragma unroll
            for (int ct = 0; ct < 4; ct++)
                acc[rt][ct] = __builtin_amdgcn_mfma_f32_16x16x32_bf16(
                    af[rt], bfr[ct], acc[rt][ct], 0, 0, 0);
    }

    // ---- epilogue ----
    float sc[4] = {0.f, 0.f, 0.f, 0.f}, qc[4] = {0.f, 0.f, 0.f, 0.f};
    #pragma unroll
    for (int rt = 0; rt < 4; rt++) {
        #pragma unroll
        for (int ct = 0; ct < 4; ct++) {
            int mrow = r0 + qr0 + rt * 16 + Q * 4;
            int ccol = c0 + qc0 + ct * 16 + n;
            f32x4 a = acc[rt][ct];
            if constexpr (OMODE == 0) {
                unsigned short* dst = (unsigned short*)Outv + (size_t)mrow * CN + ccol;
                #pragma unroll
                for (int i = 0; i < 4; i++) dst[(size_t)i * CN] = f2bf(a[i]);
            } else if constexpr (OMODE == 1) {
                float bb = bias[ccol];
                unsigned short* dst = (unsigned short*)Outv + (size_t)mrow * CN + ccol;
                #pragma unroll
                for (int i = 0; i < 4; i++) dst[(size_t)i * CN] = f2bf(a[i] + bb);
            } else if constexpr (OMODE == 2) {
                float bb = bias[ccol];
                float* dst = (float*)Outv + (size_t)mrow * CN + ccol;
                #pragma unroll
                for (int i = 0; i < 4; i++) dst[(size_t)i * CN] = a[i] + bb;
            } else if constexpr (OMODE == 3) {
                float bb = bias[ccol];
                float* dst = (float*)Outv + (size_t)mrow * CN + ccol;
                #pragma unroll
                for (int i = 0; i < 4; i++) {
                    float v = a[i] + bb;
                    dst[(size_t)i * CN] = v;
                    sc[ct] += v; qc[ct] += v * v;
                }
            } else {
                float bb = bias[ccol];
                float* dst = (float*)Outv + (size_t)mrow * CN + ccol;
                const float* rr = resid + (size_t)mrow * CN + ccol;
                #pragma unroll
                for (int i = 0; i < 4; i++) dst[(size_t)i * CN] = a[i] + bb + rr[(size_t)i * CN];
            }
        }
    }
    if constexpr (OMODE == 3) {
        #pragma unroll
        for (int ct = 0; ct < 4; ct++) {
            float s = sc[ct], q2 = qc[ct];
            s += __shfl_xor(s, 16); s += __shfl_xor(s, 32);
            q2 += __shfl_xor(q2, 16); q2 += __shfl_xor(q2, 32);
            if (Q == 0) {
                int ccol = c0 + qc0 + ct * 16 + n;
                atomicAdd(&hsum[ccol], s);
                atomicAdd(&hsq[ccol], q2);
            }
        }
    }
}

// ---- MFMA windowed attention (unchanged from R2) ----
#define PSTR 40
#define VSTR 136
__global__ __launch_bounds__(256, 2) void attn_mfma_k(
        const unsigned short* __restrict__ qkv, const int* __restrict__ widx,
        const int* __restrict__ wlen, unsigned short* __restrict__ aout) {
    __shared__ unsigned short Kl[128 * 32];
    __shared__ unsigned short Vt[32 * VSTR];
    __shared__ unsigned short Pl[4][128 * PSTR];
    const int m = blockIdx.x >> 3, h = blockIdx.x & 7;
    const int t = threadIdx.x;
    const int w = t >> 6;
    const int lane = t & 63;
    const int Q = lane >> 4, n = lane & 15;
    const int len = wlen[m];
    const int* wrow = widx + m * WWIN;
    unsigned short* Pw = Pl[w];
    const f32x4 z4 = {0.f, 0.f, 0.f, 0.f};

    const float qs = 0.17677669529663687f * 1.4426950408889634f;
    frag_ab qf[8];
    #pragma unroll
    for (int qt = 0; qt < 8; qt++) {
        int q = w * 128 + qt * 16 + n;
        int tok = wrow[q];
        uint4 u = *(const uint4*)(qkv + (size_t)tok * 768 + h * DHEAD + Q * 8);
        float f[8]; unpack8(u, f);
        uint4 r;
        r.x = pk2(f[0] * qs, f[1] * qs); r.y = pk2(f[2] * qs, f[3] * qs);
        r.z = pk2(f[4] * qs, f[5] * qs); r.w = pk2(f[6] * qs, f[7] * qs);
        qf[qt] = __builtin_bit_cast(frag_ab, r);
    }

    f32x4 Ot[2][8];
    #pragma unroll
    for (int dt = 0; dt < 2; dt++)
        #pragma unroll
        for (int qt = 0; qt < 8; qt++) Ot[dt][qt] = z4;
    float rsum[8] = {0.f, 0.f, 0.f, 0.f, 0.f, 0.f, 0.f, 0.f};

    const int nchunk = (len + 127) >> 7;
    for (int c = 0; c < nchunk; c++) {
        const int kb = c << 7;
        __syncthreads();
        if (t < 128) {
            int r = t;
            int tok = wrow[kb + r];
            const uint4* src = (const uint4*)(qkv + (size_t)tok * 768 + 512 + h * DHEAD);
            #pragma unroll
            for (int i = 0; i < 4; i++) {
                uint4 u = src[i];
                unsigned short* vp = &Vt[(i * 8) * VSTR + r];
                vp[0 * VSTR] = (unsigned short)(u.x & 0xffffu);
                vp[1 * VSTR] = (unsigned short)(u.x >> 16);
                vp[2 * VSTR] = (unsigned short)(u.y & 0xffffu);
                vp[3 * VSTR] = (unsigned short)(u.y >> 16);
                vp[4 * VSTR] = (unsigned short)(u.z & 0xffffu);
                vp[5 * VSTR] = (unsigned short)(u.z >> 16);
                vp[6 * VSTR] = (unsigned short)(u.w & 0xffffu);
                vp[7 * VSTR] = (unsigned short)(u.w >> 16);
            }
        } else {
            int r = t - 128;
            int tok = wrow[kb + r];
            const uint4* src = (const uint4*)(qkv + (size_t)tok * 768 + 256 + h * DHEAD);
            #pragma unroll
            for (int i = 0; i < 4; i++) {
                int c4 = (r + i) & 3;
                *(uint4*)&Kl[r * 32 + c4 * 8] = src[c4];
            }
        }
        __syncthreads();
        int rem = len - kb; if (rem > 128) rem = 128;
        const int nsub = (rem + 31) >> 5;
        for (int s = 0; s < nsub; s++) {
            const int lim = rem - s * 32;
            frag_ab kf0 = *(const frag_ab*)&Kl[(s * 32 + n) * 32 + Q * 8];
            frag_ab kf1 = *(const frag_ab*)&Kl[(s * 32 + 16 + n) * 32 + Q * 8];
            #pragma unroll
            for (int qt = 0; qt < 8; qt++) {
                f32x4 s0 = __builtin_amdgcn_mfma_f32_16x16x32_bf16(kf0, qf[qt], z4, 0, 0, 0);
                f32x4 s1 = __builtin_amdgcn_mfma_f32_16x16x32_bf16(kf1, qf[qt], z4, 0, 0, 0);
                float e[8];
                #pragma unroll
                for (int i = 0; i < 4; i++) {
                    e[i]     = exp2f(s0[i]);
                    e[4 + i] = exp2f(s1[i]);
                }
                if (lim < 32) {
                    #pragma unroll
                    for (int i = 0; i < 4; i++) {
                        if (4 * Q + i >= lim)      e[i] = 0.f;
                        if (16 + 4 * Q + i >= lim) e[4 + i] = 0.f;
                    }
                }
                float rsq = rsum[qt];
                #pragma unroll
                for (int i = 0; i < 8; i++) rsq += e[i];
                rsum[qt] = rsq;
                uint2 p0, p1;
                p0.x = pk2(e[0], e[1]); p0.y = pk2(e[2], e[3]);
                p1.x = pk2(e[4], e[5]); p1.y = pk2(e[6], e[7]);
                *(uint2*)&Pw[(qt * 16 + n) * PSTR + 4 * Q]      = p0;
                *(uint2*)&Pw[(qt * 16 + n) * PSTR + 16 + 4 * Q] = p1;
            }
            asm volatile("s_waitcnt lgkmcnt(0)" ::: "memory");
            frag_ab vf0 = *(const frag_ab*)&Vt[n * VSTR + s * 32 + Q * 8];
            frag_ab vf1 = *(const frag_ab*)&Vt[(16 + n) * VSTR + s * 32 + Q * 8];
            #pragma unroll
            for (int qt = 0; qt < 8; qt++) {
                frag_ab pf = *(const frag_ab*)&Pw[(qt * 16 + n) * PSTR + Q * 8];
                Ot[0][qt] = __builtin_amdgcn_mfma_f32_16x16x32_bf16(vf0, pf, Ot[0][qt], 0, 0, 0);
                Ot[1][qt] = __builtin_amdgcn_mfma_f32_16x16x32_bf16(vf1, pf, Ot[1][qt], 0, 0, 0);
            }
        }
    }

    #pragma unroll
    for (int qt = 0; qt < 8; qt++) {
        float r = rsum[qt];
        r += __shfl_xor(r, 16);
        r += __shfl_xor(r, 32);
        float inv = 1.f / r;
        int q = w * 128 + qt * 16 + n;
        unsigned short* dst = aout + ((size_t)(m * WWIN + q)) * C_DIM + h * DHEAD;
        #pragma unroll
        for (int dt = 0; dt < 2; dt++) {
            f32x4 o = Ot[dt][qt];
            uint2 pk;
            pk.x = pk2(o[0] * inv, o[1] * inv);
            pk.y = pk2(o[2] * inv, o[3] * inv);
            *(uint2*)(dst + dt * 16 + 4 * Q) = pk;
        }
    }
}

// ---- combine: x1 = x + gathered(out_proj bf16)/count, plus LN2 row stats ----
__global__ __launch_bounds__(256) void combine_k(
        const float* __restrict__ x, const unsigned short* __restrict__ proj,
        const int* __restrict__ cnt, const int* __restrict__ inv,
        float* __restrict__ x1, float* __restrict__ mu, float* __restrict__ rs) {
    int lane = threadIdx.x & 63;
    int row = blockIdx.x * 4 + (threadIdx.x >> 6);
    int c = cnt[row];
    if (c > 2) c = 2;
    float4 acc = make_float4(0.f, 0.f, 0.f, 0.f);
    for (int s = 0; s < c; s++) {
        int src = inv[row * 2 + s];
        uint2 p = ((const uint2*)(proj + (size_t)src * C_DIM))[lane];
        acc.x += bf2f(p.x & 0xffffu); acc.y += bf2f(p.x >> 16);
        acc.z += bf2f(p.y & 0xffffu); acc.w += bf2f(p.y >> 16);
    }
    float ic = 1.f / (float)(c > 0 ? c : 1);
    float4 xv = ((const float4*)(x + (size_t)row * C_DIM))[lane];
    float4 r4;
    r4.x = xv.x + acc.x * ic; r4.y = xv.y + acc.y * ic;
    r4.z = xv.z + acc.z * ic; r4.w = xv.w + acc.w * ic;
    ((float4*)(x1 + (size_t)row * C_DIM))[lane] = r4;
    float s = r4.x + r4.y + r4.z + r4.w;
    float q = r4.x * r4.x + r4.y * r4.y + r4.z * r4.z + r4.w * r4.w;
    #pragma unroll
    for (int o = 32; o; o >>= 1) { s += __shfl_xor(s, o); q += __shfl_xor(q, o); }
    if (lane == 0) {
        float mm = s * (1.f / C_DIM);
        float var = q * (1.f / C_DIM) - mm * mm;
        mu[row] = mm; rs[row] = rsqrtf(var + 1e-5f);
    }
}

__global__ void bnfin_k(const float* __restrict__ hsum, const float* __restrict__ hsq,
        const float* __restrict__ bnw, const float* __restrict__ bnb,
        float* __restrict__ premul, float* __restrict__ preadd, float inv_n) {
    int c = threadIdx.x;
    float m = hsum[c] * inv_n;
    float var = hsq[c] * inv_n - m * m;
    float rstd = rsqrtf(var + 1e-5f);
    float pm = rstd * bnw[c];
    premul[c] = pm;
    preadd[c] = bnb[c] - m * pm;
}

extern "C" void kernel_launch(void* const* d_in, const int* in_sizes, int n_in,
                              void* d_out, int out_size, void* d_ws, size_t ws_size,
                              hipStream_t stream) {
    const float* x    = (const float*)d_in[0];
    const int* widx   = (const int*)d_in[1];
    const float* ln1w = (const float*)d_in[3];
    const float* ln1b = (const float*)d_in[4];
    const float* wqkv = (const float*)d_in[5];
    const float* wproj = (const float*)d_in[6];
    const float* bproj = (const float*)d_in[7];
    const float* ln2w = (const float*)d_in[8];
    const float* ln2b = (const float*)d_in[9];
    const float* w1   = (const float*)d_in[10];
    const float* b1   = (const float*)d_in[11];
    const float* bnw  = (const float*)d_in[12];
    const float* bnb  = (const float*)d_in[13];
    const float* w2   = (const float*)d_in[14];
    const float* b2   = (const float*)d_in[15];
    float* out = (float*)d_out;

    const int N  = in_sizes[0] / C_DIM;   // 25600
    const int MW = in_sizes[1];           // M * 512
    const int M  = MW / WWIN;             // 100

    char* w = (char*)d_ws;
    size_t off = 0;
    auto alloc = [&](size_t bytes) -> void* {
        void* p = w + off;
        off += (bytes + 255) & ~(size_t)255;
        return p;
    };
    // Region A: qkv bf16 [N,768] -> out_proj bf16 [MW,256] -> h f32 [N,512]
    size_t szA = (size_t)MW * C_DIM * 4;
    void* regA = alloc(szA);
    unsigned short* qkv = (unsigned short*)regA;
    unsigned short* out_proj = (unsigned short*)regA;
    float* hbuf = (float*)regA;
    // Region B: attn_out bf16 [MW,256] -> x1 f32 [N,256]
    size_t szB = (size_t)MW * C_DIM * 2;
    void* regB = alloc(szB);
    unsigned short* attn_out = (unsigned short*)regB;
    float* x1 = (float*)regB;

    unsigned short* wqkv_bf = (unsigned short*)alloc(768 * 256 * 2);
    unsigned short* wproj_bf = (unsigned short*)alloc(256 * 256 * 2);
    unsigned short* w1_bf = (unsigned short*)alloc(512 * 256 * 2);
    unsigned short* w2_bf = (unsigned short*)alloc(256 * 512 * 2);

    float* mu0 = (float*)alloc((size_t)N * 4);
    float* rs0 = (float*)alloc((size_t)N * 4);
    float* mu1 = (float*)alloc((size_t)N * 4);
    float* rs1 = (float*)alloc((size_t)N * 4);
    int* cnt   = (int*)alloc((size_t)N * 4);
    int* inv   = (int*)alloc((size_t)N * 8);
    int* wlen  = (int*)alloc((size_t)M * 4);
    float* hsum = (float*)alloc(HID_DIM * 4);
    float* hsq  = (float*)alloc(HID_DIM * 4);
    float* premul = (float*)alloc(HID_DIM * 4);
    float* preadd = (float*)alloc(HID_DIM * 4);

    hipMemsetAsync(cnt, 0, (size_t)N * 4, stream);
    hipMemsetAsync(hsum, 0, HID_DIM * 4, stream);
    hipMemsetAsync(hsq, 0, HID_DIM * 4, stream);

    cvtw_k<<<512, 256, 0, stream>>>(wqkv, wproj, w1, w2, wqkv_bf, wproj_bf, w1_bf, w2_bf);
    rowstats_k<<<N / 4, 256, 0, stream>>>(x, mu0, rs0);
    wininv_k<<<M, 512, 0, stream>>>(widx, wlen, cnt, inv);
    // QKV = LN1(x) @ w_qkv^T   [N,768] bf16
    mgemm_k<256, 1, 0><<<dim3(768 / 128, N / 128), 256, 0, stream>>>(
        x, wqkv_bf, nullptr, qkv, mu0, rs0, ln1w, ln1b, nullptr, nullptr, nullptr, 768);
    attn_mfma_k<<<M * NHEAD, 256, 0, stream>>>(qkv, widx, wlen, attn_out);
    // out_proj = attn @ w_proj^T + b_proj   [MW,256] bf16
    mgemm_k<256, 0, 1><<<dim3(256 / 128, MW / 128), 256, 0, stream>>>(
        attn_out, wproj_bf, bproj, out_proj, nullptr, nullptr, nullptr, nullptr,
        nullptr, nullptr, nullptr, 256);
    combine_k<<<N / 4, 256, 0, stream>>>(x, out_proj, cnt, inv, x1, mu1, rs1);
    // h = LN2(x1) @ w1^T + b1, with fused BN column stats
    mgemm_k<256, 1, 3><<<dim3(512 / 128, N / 128), 256, 0, stream>>>(
        x1, w1_bf, b1, hbuf, mu1, rs1, ln2w, ln2b, nullptr, hsum, hsq, 512);
    bnfin_k<<<1, HID_DIM, 0, stream>>>(hsum, hsq, bnw, bnb, premul, preadd, 1.0f / (float)N);
    // out = x1 + relu(BN(h)) @ w2^T + b2
    mgemm_k<512, 3, 4><<<dim3(256 / 128, N / 128), 256, 0, stream>>>(
        hbuf, w2_bf, b2, out, nullptr, nullptr, premul, preadd, x1, nullptr, nullptr, 256);
}